// Round 13
// baseline (1421.952 us; speedup 1.0000x reference)
//
#include <hip/hip_runtime.h>
#include <hip/hip_bf16.h>
#include <stdint.h>
#include <stddef.h>

// ---------------- problem dims (fixed by setup_inputs) ----------------
#define M_DIM 8192
#define K_DIM 4096
#define N_DIM 16384

#define BM 256
#define BN 256
#define BK 32
#define KSTEPS (K_DIM / BK)     // 128 tiles
#define SLOT_SH (BM * BK)       // 8192 shorts = 16 KB per matrix per slot
#define NSLOT 3                 // ring: cur / next(read-ahead) / staging

typedef __attribute__((ext_vector_type(8))) short bf16x8;  // 8 bf16 = 4 VGPRs
typedef __attribute__((ext_vector_type(4))) float f32x4;
typedef __attribute__((ext_vector_type(4))) int   i32x4;

// fp32 -> bf16, round-to-nearest-even (inputs finite)
static __device__ __forceinline__ short f2bf(float f) {
    union { float f; uint32_t u; } v; v.f = f;
    uint32_t r = v.u + 0x7FFFu + ((v.u >> 16) & 1u);
    return (short)(r >> 16);
}

// FP4 E2M1 decode: low 3 bits magnitude code, bit 3 sign.
static __device__ __forceinline__ float e2m1(int v) {
    int e = (v >> 1) & 3;
    int m = v & 1;
    float mag = (e == 0) ? 0.5f * (float)m
                         : (float)(2 + m) * 0.25f * (float)(1 << e);
    return (v & 8) ? -mag : mag;
}

// async global->LDS, 16 bytes per lane; LDS dest is wave-uniform base + lane*16
static __device__ __forceinline__ void gload16(short* lds, const short* g) {
    __builtin_amdgcn_global_load_lds(
        (const __attribute__((address_space(1))) void*)g,
        (__attribute__((address_space(3))) void*)lds,
        16, 0, 0);
}

// ---------------- kernel 1: x fp32 -> bf16 ----------------
__global__ void cast_x_kernel(const float* __restrict__ x, short* __restrict__ xb) {
    size_t i = (size_t)blockIdx.x * 256 + threadIdx.x;   // one short8 per thread
    const float4* s = reinterpret_cast<const float4*>(x);
    float4 a = s[2 * i];
    float4 b = s[2 * i + 1];
    bf16x8 o;
    o[0] = f2bf(a.x); o[1] = f2bf(a.y); o[2] = f2bf(a.z); o[3] = f2bf(a.w);
    o[4] = f2bf(b.x); o[5] = f2bf(b.y); o[6] = f2bf(b.z); o[7] = f2bf(b.w);
    reinterpret_cast<bf16x8*>(xb)[i] = o;
}

// ---------------- kernel 2: dequant w_q -> bf16 [N, K] ----------------
__global__ void dequant_w_kernel(const int* __restrict__ wq,
                                 const float* __restrict__ wos,
                                 const float* __restrict__ wis,
                                 short* __restrict__ wb) {
    int tid = blockIdx.x * 256 + threadIdx.x;    // N*(K/16) = 4,194,304 total
    int n   = tid >> 8;                          // K/16 = 256 inner blocks per row
    int blk = tid & 255;
    float scale = wis[(n << 8) | blk] * wos[(n << 5) | (blk >> 3)];
    const i32x4* q = reinterpret_cast<const i32x4*>(wq + ((size_t)n << 11) + (blk << 3));
    i32x4 q0 = q[0], q1 = q[1];
    bf16x8 o0, o1;
#pragma unroll
    for (int j = 0; j < 4; ++j) {
        int c = q0[j];
        o0[2 * j]     = f2bf(e2m1(c & 15) * scale);         // even in-feature
        o0[2 * j + 1] = f2bf(e2m1((c >> 4) & 15) * scale);  // odd in-feature
    }
#pragma unroll
    for (int j = 0; j < 4; ++j) {
        int c = q1[j];
        o1[2 * j]     = f2bf(e2m1(c & 15) * scale);
        o1[2 * j + 1] = f2bf(e2m1((c >> 4) & 15) * scale);
    }
    bf16x8* dst = reinterpret_cast<bf16x8*>(wb) + 2 * (size_t)tid;
    dst[0] = o0;
    dst[1] = o1;
}

// ---------------- kernel 3: C[M,N] = A[M,K] * B[N,K]^T, bf16 in / fp32 out --
// R12: CROSS-TILE REGISTER READ-AHEAD on a 3-slot ring.
// Diagnosis R5-R11: all schedules ~5720 cyc/tile64 = MFMA + DS fully
// SERIALIZED, because each wave's MFMAs depend on ds_reads issued in the
// same tile (lgkm wait). Fix: break the dependency. 3-slot ring + stage(t+2)
// at tile-t start means the boundary vmcnt(0) entering tile t drains loads
// issued ~2 tiles (~5000 cyc) ago -- a free drain -- and guarantees tiles t
// AND t+1 are both resident during tile t. So each wave issues its 12
// ds_reads for tile t+1 (no consumer this tile -> no lgkm stall) and runs
// 32 MFMA on registers read during t-1: DS pipe drains UNDER the MFMA burst
// within each wave. Compiler emits counted lgkm before next tile's MFMA.
// Race audit: staging slot (t+2)%3 hosts tile t-1 (reads retired before the
// t-1->t barrier); read-ahead slot (t+1)%3 differs from staging slot; wrap
// ops (tt>=126) touch dead data only. One vmcnt(0)+s_barrier per tile.
// Register budget: acc 128 (AGPR) + cur frags 48 + next window <=48 -> ~233,
// 2 waves/SIMD. avN[4..7] read between the MFMA half-clusters caps the peak.
__global__ __launch_bounds__(512)
void gemm_bt_kernel(const short* __restrict__ A,
                    const short* __restrict__ B,
                    float* __restrict__ C) {
    __shared__ __align__(16) short As[NSLOT * SLOT_SH];   // 48 KB
    __shared__ __align__(16) short Bs[NSLOT * SLOT_SH];   // 48 KB

    // raster: each XCD owns an 8-wide n-stripe, n-fast (R3, FETCH-verified)
    int bid = blockIdx.x;
    int xcd = bid & 7;
    int idx = bid >> 3;          // 0..255
    int im  = idx >> 3;          // 0..31
    int in8 = idx & 7;           // 0..7
    int bm  = im << 8;
    int bn  = ((xcd << 3) + in8) << 8;

    int t    = threadIdx.x;
    int lane = t & 63;
    int w    = t >> 6;           // wave 0..7
    int wm   = w >> 2;           // 0..1
    int wn   = w & 3;            // 0..3
    int fr   = lane & 15;
    int fq   = lane >> 4;
    int wbase = w << 9;          // wave staging base (shorts): w * 512

    // staging: thread t covers row (t>>2) of each 128-row chunk, 16B slot t&3.
    // pre-swizzled global k-chunk = (t&3) ^ ((row>>1)&3)  (R4-verified, 0 conflicts)
    int gcol = (((t & 3) ^ ((t >> 3) & 3)) << 3);        // shorts
    const short* AgB = A + (size_t)(bm + (t >> 2)) * K_DIM + gcol;
    const short* BgB = B + (size_t)(bn + (t >> 2)) * K_DIM + gcol;

    // read-side swizzled slot (constant per lane): fq ^ ((fr>>1)&3)
    int slot = fq ^ ((fr >> 1) & 3);
    int aoff[8], boff[4];
#pragma unroll
    for (int mi = 0; mi < 8; ++mi)
        aoff[mi] = ((wm << 7) + mi * 16 + fr) * 4 + slot;
#pragma unroll
    for (int ni = 0; ni < 4; ++ni)
        boff[ni] = ((wn << 6) + ni * 16 + fr) * 4 + slot;

    f32x4 acc[8][4] = {};

    // one matrix K-tile = 16 KB = 2 gloads (512 thr x 16 B = 8 KB each)
#define STAGE_A(slot_, kt_)                                                   \
    do {                                                                      \
        const short* _s = AgB + (size_t)(kt_) * BK;                           \
        short* _d = As + (slot_) * SLOT_SH + wbase;                           \
        gload16(_d,        _s);                                               \
        gload16(_d + 4096, _s + (size_t)128 * K_DIM);                         \
    } while (0)
#define STAGE_B(slot_, kt_)                                                   \
    do {                                                                      \
        const short* _s = BgB + (size_t)(kt_) * BK;                           \
        short* _d = Bs + (slot_) * SLOT_SH + wbase;                           \
        gload16(_d,        _s);                                               \
        gload16(_d + 4096, _s + (size_t)128 * K_DIM);                         \
    } while (0)

    bf16x8 avP[8], bvP[4];   // ping fragment bank
    bf16x8 avQ[8], bvQ[4];   // pong fragment bank

    // prologue: stage tiles 0 (slot0) and 1 (slot1); full drain (one-time);
    // then read tile 0's fragments into P.
    STAGE_A(0, 0); STAGE_B(0, 0);
    STAGE_A(1, 1); STAGE_B(1, 1);
    asm volatile("s_waitcnt vmcnt(0)" ::: "memory");
    __builtin_amdgcn_s_barrier();
    {
        const bf16x8* Af = reinterpret_cast<const bf16x8*>(As);
        const bf16x8* Bf = reinterpret_cast<const bf16x8*>(Bs);
#pragma unroll
        for (int ni = 0; ni < 4; ++ni) bvP[ni] = Bf[boff[ni]];
#pragma unroll
        for (int mi = 0; mi < 8; ++mi) avP[mi] = Af[aoff[mi]];
    }

    // slot rotation state (wave-uniform scalars)
    int sCur = 0, sNext = 1, sStg = 2;

    // TILE body: MFMA on bank C (read 1-2 tiles ago), read-ahead bank N from
    // slot sNext (tile tt+1), stage tile tt+2 into sStg.
#define TILE(tt, avC, bvC, avN, bvN)                                          \
    do {                                                                      \
        int ktn = ((tt) + 2) & (KSTEPS - 1);  /* dead wrap at tt>=126 */      \
        STAGE_A(sStg, ktn);                                                   \
        STAGE_B(sStg, ktn);                                                   \
        const bf16x8* AfN = reinterpret_cast<const bf16x8*>(As + sNext * SLOT_SH); \
        const bf16x8* BfN = reinterpret_cast<const bf16x8*>(Bs + sNext * SLOT_SH); \
        _Pragma("unroll")                                                     \
        for (int ni = 0; ni < 4; ++ni) bvN[ni] = BfN[boff[ni]];               \
        _Pragma("unroll")                                                     \
        for (int mi = 0; mi < 4; ++mi) avN[mi] = AfN[aoff[mi]];               \
        __builtin_amdgcn_sched_barrier(0);                                    \
        __builtin_amdgcn_s_setprio(1);                                        \
        _Pragma("unroll")                                                     \
        for (int mi = 0; mi < 4; ++mi)                                        \
            _Pragma("unroll")                                                 \
            for (int ni = 0; ni < 4; ++ni)                                    \
                acc[mi][ni] = __builtin_amdgcn_mfma_f32_16x16x32_bf16(        \
                    avC[mi], bvC[ni], acc[mi][ni], 0, 0, 0);                  \
        __builtin_amdgcn_s_setprio(0);                                        \
        _Pragma("unroll")                                                     \
        for (int mi = 4; mi < 8; ++mi) avN[mi] = AfN[aoff[mi]];               \
        __builtin_amdgcn_sched_barrier(0);                                    \
        __builtin_amdgcn_s_setprio(1);                                        \
        _Pragma("unroll")                                                     \
        for (int mi = 4; mi < 8; ++mi)                                        \
            _Pragma("unroll")                                                 \
            for (int ni = 0; ni < 4; ++ni)                                    \
                acc[mi][ni] = __builtin_amdgcn_mfma_f32_16x16x32_bf16(        \
                    avC[mi], bvC[ni], acc[mi][ni], 0, 0, 0);                  \
        __builtin_amdgcn_s_setprio(0);                                        \
        /* boundary: drains stage(tt+1) issued LAST tile (~1 tile old) and   */\
        /* nothing newer is needed; stage(tt+2) just issued also drains --   */\
        /* both were issued >=0.5 tile ago; tt+1's data needed only for the  */\
        /* NEXT tile's read-ahead, which this drain+barrier guarantees.      */\
        asm volatile("s_waitcnt vmcnt(0)" ::: "memory");                      \
        __builtin_amdgcn_s_barrier();                                         \
        int _tmp = sCur; sCur = sNext; sNext = sStg; sStg = _tmp;             \
    } while (0)

    for (int tt = 0; tt < KSTEPS; tt += 2) {
        TILE(tt,     avP, bvP, avQ, bvQ);
        TILE(tt + 1, avQ, bvQ, avP, bvP);
    }
#undef TILE
#undef STAGE_A
#undef STAGE_B

    // epilogue: C/D layout col = lane&15, row = (lane>>4)*4 + reg
#pragma unroll
    for (int mi = 0; mi < 8; ++mi) {
#pragma unroll
        for (int j = 0; j < 4; ++j) {
            size_t row = (size_t)(bm + (wm << 7) + mi * 16 + fq * 4 + j);
            float* Crow = C + row * N_DIM + (bn + (wn << 6) + fr);
#pragma unroll
            for (int ni = 0; ni < 4; ++ni)
                Crow[ni * 16] = acc[mi][ni][j];
        }
    }
}

// ---------------- launch ----------------
extern "C" void kernel_launch(void* const* d_in, const int* in_sizes, int n_in,
                              void* d_out, int out_size, void* d_ws, size_t ws_size,
                              hipStream_t stream) {
    const float* x   = (const float*)d_in[0];
    const int*   wq  = (const int*)d_in[1];
    const float* wos = (const float*)d_in[2];
    const float* wis = (const float*)d_in[3];
    float* out = (float*)d_out;

    short* xb = (short*)d_ws;                                        // 64 MB
    short* wb = (short*)((char*)d_ws + (size_t)M_DIM * K_DIM * 2);   // 128 MB

    cast_x_kernel<<<(M_DIM * (size_t)K_DIM / 8) / 256, 256, 0, stream>>>(x, xb);
    dequant_w_kernel<<<(N_DIM * (size_t)K_DIM / 16) / 256, 256, 0, stream>>>(wq, wos, wis, wb);
    gemm_bt_kernel<<<(M_DIM / BM) * (N_DIM / BN), 512, 0, stream>>>(xb, wb, out);
}